// Round 16
// baseline (168.352 us; speedup 1.0000x reference)
//
#include <hip/hip_runtime.h>
#include <hip/hip_bf16.h>

#define IN_DIM  128
#define OUT_DIM 64
#define EPB 4096          // edges per count/partition block
#define NBK_MAX 512       // max coarse buckets (n <= 131072)

typedef short  bf16x8 __attribute__((ext_vector_type(8)));
typedef float  f32x4  __attribute__((ext_vector_type(4)));

__device__ __forceinline__ unsigned short f2bf(float f) {   // RNE
    unsigned u = __float_as_uint(f);
    u += 0x7fffu + ((u >> 16) & 1u);
    return (unsigned short)(u >> 16);
}
__device__ __forceinline__ float bf2f(unsigned short h) {
    return __uint_as_float((unsigned)h << 16);
}

// ---------------------------------------------------------------------------
// CSR build, two-level LDS counting sort (no global atomics).
// Bucket = dst >> 8 (256 nodes per bucket). Record = (dst&255)<<17 | src (u32).
// ---------------------------------------------------------------------------

// Phase 1: per-block coarse histogram -> colcnt[bucket][blk]
__global__ __launch_bounds__(256) void k_cnt(const int* __restrict__ dst,
                                             unsigned* __restrict__ colcnt,
                                             int nE, int nbk, int nblk) {
    __shared__ unsigned h[NBK_MAX];
    for (int b = threadIdx.x; b < NBK_MAX; b += 256) h[b] = 0u;
    __syncthreads();
    int blk = blockIdx.x;
    int e0 = blk * EPB, e1 = min(e0 + EPB, nE);
    for (int e = e0 + threadIdx.x; e < e1; e += 256)
        atomicAdd(&h[dst[e] >> 8], 1u);
    __syncthreads();
    for (int b = threadIdx.x; b < nbk; b += 256)
        colcnt[(size_t)b * nblk + blk] = h[b];
}

// Phase 2a: per-bucket exclusive scan over blocks (in place); totals out.
__global__ __launch_bounds__(512) void k_bsum(unsigned* __restrict__ colcnt,
                                              unsigned* __restrict__ btot,
                                              int nbk, int nblk) {
    __shared__ unsigned s[512];
    int b = blockIdx.x;
    unsigned v = (threadIdx.x < (unsigned)nblk) ? colcnt[(size_t)b * nblk + threadIdx.x] : 0u;
    s[threadIdx.x] = v;
    __syncthreads();
    for (int d = 1; d < 512; d <<= 1) {
        unsigned t = (threadIdx.x >= (unsigned)d) ? s[threadIdx.x - d] : 0u;
        __syncthreads();
        s[threadIdx.x] += t;
        __syncthreads();
    }
    if (threadIdx.x < (unsigned)nblk)
        colcnt[(size_t)b * nblk + threadIdx.x] = s[threadIdx.x] - v;
    if (threadIdx.x == 511) btot[b] = s[511];
}

// Phase 2b: scan bucket totals -> bbase[0..nbk], bbase[nbk] = nE.
__global__ __launch_bounds__(512) void k_btots(const unsigned* __restrict__ btot,
                                               unsigned* __restrict__ bbase,
                                               int nbk, int nE) {
    __shared__ unsigned s[512];
    unsigned v = (threadIdx.x < (unsigned)nbk) ? btot[threadIdx.x] : 0u;
    s[threadIdx.x] = v;
    __syncthreads();
    for (int d = 1; d < 512; d <<= 1) {
        unsigned t = (threadIdx.x >= (unsigned)d) ? s[threadIdx.x - d] : 0u;
        __syncthreads();
        s[threadIdx.x] += t;
        __syncthreads();
    }
    if (threadIdx.x < (unsigned)nbk) bbase[threadIdx.x] = s[threadIdx.x] - v;
    if (threadIdx.x == 0) bbase[nbk] = (unsigned)nE;
}

// Phase 3: partition edges into bucket-grouped u32 records.
__global__ __launch_bounds__(256) void k_part(const int* __restrict__ src,
                                              const int* __restrict__ dst,
                                              const unsigned* __restrict__ colcnt,
                                              const unsigned* __restrict__ bbase,
                                              unsigned* __restrict__ ebuf,
                                              int nE, int nbk, int nblk) {
    __shared__ unsigned curs[NBK_MAX];
    int blk = blockIdx.x;
    for (int b = threadIdx.x; b < nbk; b += 256)
        curs[b] = bbase[b] + colcnt[(size_t)b * nblk + blk];
    __syncthreads();
    int e0 = blk * EPB, e1 = min(e0 + EPB, nE);
    for (int e = e0 + threadIdx.x; e < e1; e += 256) {
        int d = dst[e], s = src[e];
        unsigned p = atomicAdd(&curs[d >> 8], 1u);
        ebuf[p] = ((unsigned)(d & 255) << 17) | (unsigned)s;   // src < 2^17
    }
}

// Phase 4: per-bucket fine pass -> offs, dinv, perm.
__global__ __launch_bounds__(256) void k_fine(const unsigned* __restrict__ ebuf,
                                              const unsigned* __restrict__ bbase,
                                              unsigned* __restrict__ offs,
                                              float* __restrict__ dinv,
                                              int* __restrict__ perm, int n) {
    __shared__ unsigned deg[256], pos[256], cur[256];
    int b = blockIdx.x;
    int node0 = b << 8;
    unsigned ebeg = bbase[b], eend = bbase[b + 1];
    deg[threadIdx.x] = 0u;
    __syncthreads();
    for (unsigned e = ebeg + threadIdx.x; e < eend; e += 256)
        atomicAdd(&deg[ebuf[e] >> 17], 1u);
    __syncthreads();
    unsigned v = deg[threadIdx.x];
    pos[threadIdx.x] = v;
    __syncthreads();
    for (int d = 1; d < 256; d <<= 1) {
        unsigned t = (threadIdx.x >= (unsigned)d) ? pos[threadIdx.x - d] : 0u;
        __syncthreads();
        pos[threadIdx.x] += t;
        __syncthreads();
    }
    unsigned excl = pos[threadIdx.x] - v;
    cur[threadIdx.x] = excl;
    int node = node0 + threadIdx.x;
    if (node < n) {
        offs[node] = ebeg + excl;
        dinv[node] = rsqrtf((float)v + 1.0f);    // +1 self-loop
    }
    __syncthreads();
    for (unsigned e = ebeg + threadIdx.x; e < eend; e += 256) {
        unsigned rec = ebuf[e];
        unsigned p = atomicAdd(&cur[rec >> 17], 1u);
        perm[ebeg + p] = (int)(rec & 0x1FFFFu);  // src
    }
}

// ---------------------------------------------------------------------------
// MFMA linear layer (R13-proven): out[r] = dinv[r]*(f(in[r]) @ W), bf16 hi/lo
// split (hh+hl+lh terms ~ f32 precision). 64 rows/block, 4 waves x 16-row
// stripes; W->LDS transposed+padded bf16; mfma_f32_16x16x32_bf16.
// ---------------------------------------------------------------------------
template <int KD, bool RELU>
__global__ __launch_bounds__(256) void k_linm(const float* __restrict__ in,
                                              const float* __restrict__ W,   // [KD][64]
                                              const float* __restrict__ dinv,
                                              unsigned short* __restrict__ outp, int n) {
    constexpr int LDK = KD + 8;
    __shared__ unsigned short WH[64 * LDK];
    __shared__ unsigned short WL[64 * LDK];
    for (int i = threadIdx.x; i < KD * 64; i += 256) {
        int k = i >> 6, c = i & 63;
        float wv = W[i];
        unsigned short h = f2bf(wv);
        WH[c * LDK + k] = h;
        WL[c * LDK + k] = f2bf(wv - bf2f(h));
    }
    __syncthreads();

    int wid = threadIdx.x >> 6, lane = threadIdx.x & 63;
    int r0 = blockIdx.x * 64 + wid * 16;

    constexpr int NK = KD / 32;
    int arow = r0 + (lane & 15);
    int ar = arow < n ? arow : (n - 1);
    int k8 = (lane >> 4) * 8;

    bf16x8 ah[NK], al[NK];
    {
        const float* rp = in + (size_t)ar * KD;
        float dvin = RELU ? dinv[ar] : 0.f;
#pragma unroll
        for (int ks = 0; ks < NK; ++ks) {
            float4 v0 = *(const float4*)(rp + ks * 32 + k8);
            float4 v1 = *(const float4*)(rp + ks * 32 + k8 + 4);
            float xv[8] = {v0.x, v0.y, v0.z, v0.w, v1.x, v1.y, v1.z, v1.w};
#pragma unroll
            for (int j = 0; j < 8; ++j) {
                float f = xv[j];
                if (RELU) f = fmaxf(dvin * f, 0.f);
                unsigned short h = f2bf(f);
                ah[ks][j] = (short)h;
                al[ks][j] = (short)f2bf(f - bf2f(h));
            }
        }
    }

    f32x4 acc[4];
#pragma unroll
    for (int nt = 0; nt < 4; ++nt) {
        int col = nt * 16 + (lane & 15);
        const unsigned short* bh = &WH[col * LDK + k8];
        const unsigned short* bl = &WL[col * LDK + k8];
        f32x4 a = {0.f, 0.f, 0.f, 0.f};
#pragma unroll
        for (int ks = 0; ks < NK; ++ks) {
            bf16x8 Bh = *(const bf16x8*)(bh + ks * 32);
            bf16x8 Bl = *(const bf16x8*)(bl + ks * 32);
            a = __builtin_amdgcn_mfma_f32_16x16x32_bf16(ah[ks], Bh, a, 0, 0, 0);
            a = __builtin_amdgcn_mfma_f32_16x16x32_bf16(ah[ks], Bl, a, 0, 0, 0);
            a = __builtin_amdgcn_mfma_f32_16x16x32_bf16(al[ks], Bh, a, 0, 0, 0);
        }
        acc[nt] = a;
    }

    int orow0 = r0 + (lane >> 4) * 4;
#pragma unroll
    for (int j = 0; j < 4; ++j) {
        int row = orow0 + j;
        if (row < n) {
            float dv = dinv[row];
#pragma unroll
            for (int nt = 0; nt < 4; ++nt)
                outp[(size_t)row * 64 + nt * 16 + (lane & 15)] = f2bf(dv * acc[nt][j]);
        }
    }
}

// ---------------------------------------------------------------------------
// CSR gather, group-per-node: wave = 4 groups x 16 lanes; group g OWNS node
// (wavebase + g): gathers its rows (16 lanes x ushort4 = 128B row), keeps its
// own f32 accumulators, stores its own 256B f32 row. No cross-group combine.
// Groups run lockstep to max-degree-of-4 with per-edge predication.
// 4-way k-unroll keeps 4 loads in flight per wave.
// ---------------------------------------------------------------------------
template <bool FIN>
__global__ __launch_bounds__(256) void k_gather(const unsigned short* __restrict__ hs,
                                                const unsigned* __restrict__ offs,
                                                const int* __restrict__ perm,
                                                const float* __restrict__ dinv,
                                                float* __restrict__ outb,
                                                int n, int nE) {
    int lane = threadIdx.x & 63;
    int g = lane >> 4, li = lane & 15;
    int r = (blockIdx.x * 4 + (threadIdx.x >> 6)) * 4 + g;   // 16 nodes per block
    bool nvalid = r < n;
    int rc = nvalid ? r : (n - 1);
    unsigned beg = offs[rc];
    unsigned end = (rc + 1 < n) ? offs[rc + 1] : (unsigned)nE;
    unsigned deg = nvalid ? (end - beg) : 0u;

    // self-loop term
    float4 q0, q1 = {0.f,0.f,0.f,0.f}, q2 = q1, q3 = q1;
    {
        ushort4 sv = *(const ushort4*)(hs + (size_t)rc * 64 + li * 4);
        q0.x = bf2f(sv.x); q0.y = bf2f(sv.y); q0.z = bf2f(sv.z); q0.w = bf2f(sv.w);
    }

    // max degree across the wave's 4 groups (uniform after 2 xors)
    unsigned m1 = max(deg, (unsigned)__shfl_xor((int)deg, 16));
    unsigned mdeg = max(m1, (unsigned)__shfl_xor((int)m1, 32));

    for (unsigned c0 = 0; c0 < mdeg; c0 += 16) {
        int sl = 0;
        if (c0 + li < deg) sl = perm[beg + c0 + li];     // per-group 64B segment
        unsigned rem = mdeg - c0;
        unsigned kmax = rem < 16u ? rem : 16u;           // wave-uniform
        for (unsigned k = 0; k < kmax; k += 4) {
            int s0 = __shfl(sl, (int)(g * 16) + (int)k);
            int s1 = __shfl(sl, (int)(g * 16) + (int)k + 1);
            int s2 = __shfl(sl, (int)(g * 16) + (int)k + 2);
            int s3 = __shfl(sl, (int)(g * 16) + (int)k + 3);
            unsigned d0 = c0 + k;
            if (d0 < deg) {
                ushort4 v = *(const ushort4*)(hs + (size_t)s0 * 64 + li * 4);
                q0.x += bf2f(v.x); q0.y += bf2f(v.y); q0.z += bf2f(v.z); q0.w += bf2f(v.w);
            }
            if (d0 + 1 < deg) {
                ushort4 v = *(const ushort4*)(hs + (size_t)s1 * 64 + li * 4);
                q1.x += bf2f(v.x); q1.y += bf2f(v.y); q1.z += bf2f(v.z); q1.w += bf2f(v.w);
            }
            if (d0 + 2 < deg) {
                ushort4 v = *(const ushort4*)(hs + (size_t)s2 * 64 + li * 4);
                q2.x += bf2f(v.x); q2.y += bf2f(v.y); q2.z += bf2f(v.z); q2.w += bf2f(v.w);
            }
            if (d0 + 3 < deg) {
                ushort4 v = *(const ushort4*)(hs + (size_t)s3 * 64 + li * 4);
                q3.x += bf2f(v.x); q3.y += bf2f(v.y); q3.z += bf2f(v.z); q3.w += bf2f(v.w);
            }
        }
    }

    if (nvalid) {
        float4 acc;
        acc.x = (q0.x + q1.x) + (q2.x + q3.x);
        acc.y = (q0.y + q1.y) + (q2.y + q3.y);
        acc.z = (q0.z + q1.z) + (q2.z + q3.z);
        acc.w = (q0.w + q1.w) + (q2.w + q3.w);
        if (FIN) {
            float dv = dinv[r];
            acc.x *= dv; acc.y *= dv; acc.z *= dv; acc.w *= dv;
        }
        *(float4*)(outb + (size_t)r * 64 + li * 4) = acc;    // 256B per group
    }
}

// ---------------------------------------------------------------------------
extern "C" void kernel_launch(void* const* d_in, const int* in_sizes, int n_in,
                              void* d_out, int out_size, void* d_ws, size_t ws_size,
                              hipStream_t stream) {
    const float* x  = (const float*)d_in[0];
    const int*   ei = (const int*)d_in[1];
    const float* W1 = (const float*)d_in[2];
    const float* W2 = (const float*)d_in[3];
    float* out = (float*)d_out;

    int n  = in_sizes[0] / IN_DIM;   // 100000
    int nE = in_sizes[1] / 2;        // 1600000
    const int* src = ei;
    const int* dst = ei + nE;

    int nbk  = (n + 255) >> 8;               // coarse buckets (391)
    int nblk = (nE + EPB - 1) / EPB;         // count/partition blocks (391)

    // workspace carve-up (256B-aligned); d_out doubles as the layer-1 agg buffer
    char* w = (char*)d_ws;
    size_t nAl = ((size_t)n * 4 + 255) & ~(size_t)255;
    float*          dinv   = (float*)w;     w += nAl;
    unsigned*       offs   = (unsigned*)w;  w += nAl;
    unsigned*       colcnt = (unsigned*)w;  w += ((size_t)nbk * nblk * 4 + 255) & ~(size_t)255;
    unsigned*       btot   = (unsigned*)w;  w += ((size_t)nbk * 4 + 255) & ~(size_t)255;
    unsigned*       bbase  = (unsigned*)w;  w += ((size_t)(nbk + 1) * 4 + 255) & ~(size_t)255;
    unsigned*       ebuf   = (unsigned*)w;  w += ((size_t)nE * 4 + 255) & ~(size_t)255;
    int*            perm   = (int*)w;       w += ((size_t)nE * 4 + 255) & ~(size_t)255;
    unsigned short* hs     = (unsigned short*)w; w += (size_t)n * 64 * 2;
    float*          agg    = out;            // layer-1 aggregate lives in d_out

    int gRow = (n + 15) / 16;        // 16 nodes per gather block
    int gMf  = (n + 63) / 64;

    // --- CSR build: two-level LDS counting sort ---
    k_cnt  <<<nblk, 256, 0, stream>>>(dst, colcnt, nE, nbk, nblk);
    k_bsum <<<nbk,  512, 0, stream>>>(colcnt, btot, nbk, nblk);
    k_btots<<<1,    512, 0, stream>>>(btot, bbase, nbk, nE);
    k_part <<<nblk, 256, 0, stream>>>(src, dst, colcnt, bbase, ebuf, nE, nbk, nblk);
    k_fine <<<nbk,  256, 0, stream>>>(ebuf, bbase, offs, dinv, perm, n);

    // --- layer 1 ---
    k_linm<IN_DIM, false><<<gMf, 256, 0, stream>>>(x, W1, dinv, hs, n);
    k_gather<false><<<gRow, 256, 0, stream>>>(hs, offs, perm, dinv, agg, n, nE);

    // --- layer 2 (reuse hs; final dinv folded into gather) ---
    k_linm<OUT_DIM, true><<<gMf, 256, 0, stream>>>(agg, W2, dinv, hs, n);
    k_gather<true><<<gRow, 256, 0, stream>>>(hs, offs, perm, dinv, out, n, nE);
}